// Round 3
// baseline (975.573 us; speedup 1.0000x reference)
//
#include <hip/hip_runtime.h>
#include <hip/hip_bf16.h>

#define N_NODES 100000
#define N_EDGES 1600000
#define FDIM 128
#define NCLS 40
#define NCLS_PAD 48

#define SCAN_BLK 1024
#define SCAN_NB ((N_NODES + SCAN_BLK - 1) / SCAN_BLK)   // 98
#define NBUCK ((N_NODES + 255) / 256)                   // 391 buckets of 256 nodes

typedef __attribute__((ext_vector_type(8))) short short8;
typedef __attribute__((ext_vector_type(4))) float f32x4;

__device__ __forceinline__ float bf2f(unsigned short u) {
    union { unsigned int i; float f; } v; v.i = ((unsigned int)u) << 16; return v.f;
}
__device__ __forceinline__ unsigned short f2bf(float f) {
    __hip_bfloat16 h = __float2bfloat16(f);
    return *reinterpret_cast<unsigned short*>(&h);
}

// ---------------- fp32 -> bf16 bulk convert (vectorized) ----------------
__global__ void k_cvt_bf16(const float4* __restrict__ in, ushort4* __restrict__ out, int n4) {
    int i = blockIdx.x * blockDim.x + threadIdx.x;
    if (i >= n4) return;
    float4 v = in[i];
    ushort4 o;
    o.x = f2bf(v.x); o.y = f2bf(v.y); o.z = f2bf(v.z); o.w = f2bf(v.w);
    out[i] = o;
}

// ---------------- degree histogram ----------------
__global__ void k_hist(const int* __restrict__ dst, unsigned* __restrict__ cnt) {
    int e = blockIdx.x * blockDim.x + threadIdx.x;
    if (e < N_EDGES) atomicAdd(&cnt[dst[e]], 1u);
}

// ---------------- hierarchical exclusive scan ----------------
__global__ __launch_bounds__(SCAN_BLK) void k_scan_local(
        const unsigned* __restrict__ cnt, int* __restrict__ rowptr,
        unsigned* __restrict__ bsum) {
    __shared__ unsigned lds[SCAN_BLK];
    int t = threadIdx.x;
    int gid = blockIdx.x * SCAN_BLK + t;
    unsigned v = (gid < N_NODES) ? cnt[gid] : 0u;
    lds[t] = v;
    __syncthreads();
    for (int d = 1; d < SCAN_BLK; d <<= 1) {
        unsigned add = (t >= d) ? lds[t - d] : 0u;
        __syncthreads();
        lds[t] += add;
        __syncthreads();
    }
    if (gid < N_NODES) rowptr[gid] = (int)(lds[t] - v);   // exclusive within block
    if (t == SCAN_BLK - 1) bsum[blockIdx.x] = lds[t];
}

__global__ void k_scan_bsum(const unsigned* __restrict__ bsum, unsigned* __restrict__ boff) {
    __shared__ unsigned lds[128];
    int t = threadIdx.x;
    unsigned v = (t < SCAN_NB) ? bsum[t] : 0u;
    lds[t] = v;
    __syncthreads();
    for (int d = 1; d < 128; d <<= 1) {
        unsigned add = (t >= d) ? lds[t - d] : 0u;
        __syncthreads();
        lds[t] += add;
        __syncthreads();
    }
    if (t < SCAN_NB) boff[t] = lds[t] - v;
}

__global__ __launch_bounds__(SCAN_BLK) void k_scan_add(
        int* __restrict__ rowptr, const unsigned* __restrict__ boff) {
    int gid = blockIdx.x * SCAN_BLK + threadIdx.x;
    if (gid < N_NODES) rowptr[gid] += (int)boff[blockIdx.x];
    if (gid == 0) rowptr[N_NODES] = N_EDGES;
}

// ---------------- phase A: bin edges into 256-node buckets (dense 8B writes) ----------------
__global__ void k_binpack(const int* __restrict__ src, const int* __restrict__ dst,
                          const int* __restrict__ rowptr, unsigned* __restrict__ bfill,
                          unsigned long long* __restrict__ bpack) {
    int e = blockIdx.x * blockDim.x + threadIdx.x;
    if (e >= N_EDGES) return;
    int d = dst[e];
    int b = d >> 8;
    int slot = rowptr[b << 8] + (int)atomicAdd(&bfill[b], 1u);
    bpack[slot] = ((unsigned long long)(unsigned)d << 32) | (unsigned)src[e];
}

// ---------------- phase B: scatter within buckets (writes confined to ~16KB regions) ----------------
__global__ void k_scatter2(const unsigned long long* __restrict__ bpack,
                           const int* __restrict__ rowptr, unsigned* __restrict__ cur,
                           int* __restrict__ esrc) {
    int e = blockIdx.x * blockDim.x + threadIdx.x;
    if (e >= N_EDGES) return;
    unsigned long long p = bpack[e];
    int s = (int)(unsigned)p;
    int d = (int)(p >> 32);
    int slot = rowptr[d] + (int)atomicAdd(&cur[d], 1u);
    esrc[slot] = s;
}

// ---------------- mean aggregation ----------------
// one wave per node; 16 lanes x short8 (16B) cover a 256B feature row;
// 4 edges in flight per wave-iteration; cross-group reduce via shfl_xor.
__global__ void k_aggregate(const unsigned short* __restrict__ feat,
                            const int* __restrict__ esrc,
                            const int* __restrict__ rowptr,
                            unsigned short* __restrict__ out) {
    int node = blockIdx.x * 4 + (threadIdx.x >> 6);
    if (node >= N_NODES) return;
    int lane = threadIdx.x & 63;
    int sub = lane >> 4;          // which of 4 concurrent edges
    int fl = lane & 15;           // feature lane: feats [fl*8, fl*8+8)
    int s = rowptr[node], e = rowptr[node + 1];
    float acc[8];
#pragma unroll
    for (int q = 0; q < 8; ++q) acc[q] = 0.f;

    for (int j = s + sub; j < e; j += 4) {
        int sv = esrc[j];
        short8 v = *(const short8*)(feat + (size_t)sv * FDIM + fl * 8);
#pragma unroll
        for (int q = 0; q < 8; ++q) acc[q] += bf2f((unsigned short)v[q]);
    }
#pragma unroll
    for (int q = 0; q < 8; ++q) {
        acc[q] += __shfl_xor(acc[q], 16, 64);
        acc[q] += __shfl_xor(acc[q], 32, 64);
    }
    int deg = e - s;
    float inv = 1.0f / (float)(deg > 1 ? deg : 1);
    if (sub == 0) {
        short8 o;
#pragma unroll
        for (int q = 0; q < 8; ++q) o[q] = (short)f2bf(acc[q] * inv);
        *(short8*)(out + (size_t)node * FDIM + fl * 8) = o;
    }
}

// ---------------- pack weights: Bp[col][k] = W[k][col], bf16; pad cols with 0 ----------------
__global__ void k_pack(const float* __restrict__ Wl, const float* __restrict__ Wr,
                       const float* __restrict__ bin, unsigned short* __restrict__ Bp,
                       float* __restrict__ bout, int ncols_out, int ncols_src, int Keach) {
    int K = (Wr != nullptr) ? 2 * Keach : Keach;
    int idx = blockIdx.x * blockDim.x + threadIdx.x;
    if (idx >= ncols_out * K) return;
    int col = idx / K, k = idx % K;
    float v = 0.f;
    if (col < ncols_src)
        v = (k < Keach) ? Wl[(size_t)k * ncols_src + col]
                        : Wr[(size_t)(k - Keach) * ncols_src + col];
    Bp[(size_t)col * K + k] = f2bf(v);
    if (k == 0) bout[col] = (col < ncols_src) ? bin[col] : 0.f;
}

// ---------------- fused layer GEMM: out = relu([A0 | A1] @ Bp^T + bias), bf16 out ----------------
__global__ __launch_bounds__(256) void k_gemm_layer(
        const unsigned short* __restrict__ A0, const unsigned short* __restrict__ A1,
        const unsigned short* __restrict__ Bp, const float* __restrict__ bias,
        unsigned short* __restrict__ out) {
    int wave = threadIdx.x >> 6;
    int lane = threadIdx.x & 63;
    int rowblk = blockIdx.x * 64 + wave * 16;
    int lrow = lane & 15;
    int kgrp = lane >> 4;
    int arow = rowblk + lrow; if (arow > N_NODES - 1) arow = N_NODES - 1;

    f32x4 acc[8];
#pragma unroll
    for (int c = 0; c < 8; ++c) acc[c] = (f32x4){0.f, 0.f, 0.f, 0.f};

#pragma unroll
    for (int kb = 0; kb < 8; ++kb) {
        const unsigned short* Asrc = (kb < 4) ? A0 : A1;
        int kk = (kb & 3) * 32 + kgrp * 8;
        short8 a = *(const short8*)(Asrc + (size_t)arow * FDIM + kk);
        int kB = kb * 32 + kgrp * 8;
#pragma unroll
        for (int c = 0; c < 8; ++c) {
            short8 b = *(const short8*)(Bp + (size_t)(c * 16 + lrow) * 256 + kB);
            acc[c] = __builtin_amdgcn_mfma_f32_16x16x32_bf16(a, b, acc[c], 0, 0, 0);
        }
    }

    int orowbase = rowblk + kgrp * 4;
#pragma unroll
    for (int c = 0; c < 8; ++c) {
        int col = c * 16 + lrow;
        float bv = bias[col];
#pragma unroll
        for (int i = 0; i < 4; ++i) {
            int r = orowbase + i;
            if (r < N_NODES) {
                float v = acc[c][i] + bv;
                v = fmaxf(v, 0.f);
                out[(size_t)r * FDIM + col] = f2bf(v);
            }
        }
    }
}

// ---------------- output GEMM: out = A0 @ Bp^T + bias, fp32 out [N][40], K = 128 ----------------
__global__ __launch_bounds__(256) void k_gemm_out(
        const unsigned short* __restrict__ A0, const unsigned short* __restrict__ Bp,
        const float* __restrict__ bias, float* __restrict__ out) {
    int wave = threadIdx.x >> 6;
    int lane = threadIdx.x & 63;
    int rowblk = blockIdx.x * 64 + wave * 16;
    int lrow = lane & 15;
    int kgrp = lane >> 4;
    int arow = rowblk + lrow; if (arow > N_NODES - 1) arow = N_NODES - 1;

    f32x4 acc[3];
#pragma unroll
    for (int c = 0; c < 3; ++c) acc[c] = (f32x4){0.f, 0.f, 0.f, 0.f};

#pragma unroll
    for (int kb = 0; kb < 4; ++kb) {
        int kk = kb * 32 + kgrp * 8;
        short8 a = *(const short8*)(A0 + (size_t)arow * FDIM + kk);
#pragma unroll
        for (int c = 0; c < 3; ++c) {
            short8 b = *(const short8*)(Bp + (size_t)(c * 16 + lrow) * FDIM + kk);
            acc[c] = __builtin_amdgcn_mfma_f32_16x16x32_bf16(a, b, acc[c], 0, 0, 0);
        }
    }

    int orowbase = rowblk + kgrp * 4;
#pragma unroll
    for (int c = 0; c < 3; ++c) {
        int col = c * 16 + lrow;
        if (col < NCLS) {
            float bv = bias[col];
#pragma unroll
            for (int i = 0; i < 4; ++i) {
                int r = orowbase + i;
                if (r < N_NODES)
                    out[(size_t)r * NCLS + col] = acc[c][i] + bv;
            }
        }
    }
}

extern "C" void kernel_launch(void* const* d_in, const int* in_sizes, int n_in,
                              void* d_out, int out_size, void* d_ws, size_t ws_size,
                              hipStream_t stream) {
    const float* x    = (const float*)d_in[0];
    const int*   ei   = (const int*)d_in[1];
    const float* W1l  = (const float*)d_in[2];
    const float* W1r  = (const float*)d_in[3];
    const float* b1   = (const float*)d_in[4];
    const float* W2l  = (const float*)d_in[5];
    const float* W2r  = (const float*)d_in[6];
    const float* b2   = (const float*)d_in[7];
    const float* Wout = (const float*)d_in[8];
    const float* bout = (const float*)d_in[9];
    const int* src = ei;
    const int* dst = ei + N_EDGES;

    char* ws = (char*)d_ws;
    size_t off = 0;
    auto alloc = [&](size_t bytes) -> void* {
        void* p = ws + off;
        off += (bytes + 255) & ~(size_t)255;
        return p;
    };
    unsigned short* xb   = (unsigned short*)alloc((size_t)N_NODES * FDIM * 2);
    unsigned short* aggn = (unsigned short*)alloc((size_t)N_NODES * FDIM * 2);
    unsigned short* h1   = (unsigned short*)alloc((size_t)N_NODES * FDIM * 2);
    unsigned short* h2   = (unsigned short*)alloc((size_t)N_NODES * FDIM * 2);
    unsigned short* Bp1  = (unsigned short*)alloc((size_t)FDIM * 256 * 2);
    unsigned short* Bp2  = (unsigned short*)alloc((size_t)FDIM * 256 * 2);
    unsigned short* Bp3  = (unsigned short*)alloc((size_t)NCLS_PAD * FDIM * 2);
    float* b1p = (float*)alloc(FDIM * 4);
    float* b2p = (float*)alloc(FDIM * 4);
    float* b3p = (float*)alloc(NCLS_PAD * 4);
    unsigned* cnt  = (unsigned*)alloc((size_t)N_NODES * 4);
    unsigned* cur  = (unsigned*)alloc((size_t)N_NODES * 4);
    int* rowptr    = (int*)alloc((size_t)(N_NODES + 1) * 4);
    int* esrc      = (int*)alloc((size_t)N_EDGES * 4);
    unsigned* bsum = (unsigned*)alloc((size_t)SCAN_NB * 4);
    unsigned* boff = (unsigned*)alloc((size_t)SCAN_NB * 4);
    unsigned* bfill = (unsigned*)alloc((size_t)NBUCK * 4);
    unsigned long long* bpack = (unsigned long long*)alloc((size_t)N_EDGES * 8);

    hipMemsetAsync(cnt, 0, (size_t)N_NODES * 4, stream);
    hipMemsetAsync(cur, 0, (size_t)N_NODES * 4, stream);
    hipMemsetAsync(bfill, 0, (size_t)NBUCK * 4, stream);

    // bf16 copy of x
    int n4 = N_NODES * FDIM / 4;
    k_cvt_bf16<<<(n4 + 255) / 256, 256, 0, stream>>>((const float4*)x, (ushort4*)xb, n4);

    // weight packs
    k_pack<<<(FDIM * 256 + 255) / 256, 256, 0, stream>>>(W1l, W1r, b1, Bp1, b1p, FDIM, FDIM, FDIM);
    k_pack<<<(FDIM * 256 + 255) / 256, 256, 0, stream>>>(W2l, W2r, b2, Bp2, b2p, FDIM, FDIM, FDIM);
    k_pack<<<(NCLS_PAD * FDIM + 255) / 256, 256, 0, stream>>>(Wout, nullptr, bout, Bp3, b3p, NCLS_PAD, NCLS, FDIM);

    // CSR build
    k_hist<<<(N_EDGES + 255) / 256, 256, 0, stream>>>(dst, cnt);
    k_scan_local<<<SCAN_NB, SCAN_BLK, 0, stream>>>(cnt, rowptr, bsum);
    k_scan_bsum<<<1, 128, 0, stream>>>(bsum, boff);
    k_scan_add<<<SCAN_NB, SCAN_BLK, 0, stream>>>(rowptr, boff);
    k_binpack<<<(N_EDGES + 255) / 256, 256, 0, stream>>>(src, dst, rowptr, bfill, bpack);
    k_scatter2<<<(N_EDGES + 255) / 256, 256, 0, stream>>>(bpack, rowptr, cur, esrc);

    int aggGrid = (N_NODES + 3) / 4;
    int gemmGrid = (N_NODES + 63) / 64;

    // layer 1
    k_aggregate<<<aggGrid, 256, 0, stream>>>(xb, esrc, rowptr, aggn);
    k_gemm_layer<<<gemmGrid, 256, 0, stream>>>(aggn, xb, Bp1, b1p, h1);
    // layer 2
    k_aggregate<<<aggGrid, 256, 0, stream>>>(h1, esrc, rowptr, aggn);
    k_gemm_layer<<<gemmGrid, 256, 0, stream>>>(aggn, h1, Bp2, b2p, h2);
    // head
    k_gemm_out<<<gemmGrid, 256, 0, stream>>>(h2, Bp3, b3p, (float*)d_out);
}

// Round 4
// 449.530 us; speedup vs baseline: 2.1702x; 2.1702x over previous
//
#include <hip/hip_runtime.h>
#include <hip/hip_bf16.h>

#define N_NODES 100000
#define N_EDGES 1600000
#define FDIM 128
#define NCLS 40
#define NCLS_PAD 48

#define SCAN_BLK 1024
#define SCAN_NB ((N_NODES + SCAN_BLK - 1) / SCAN_BLK)   // 98

#define NREG 8
#define REG_SZ ((N_NODES + NREG - 1) / NREG)            // 12500 nodes per region
#define NCHUNK 128
#define CHUNK_SZ (N_EDGES / NCHUNK)                     // 12500 edges per chunk

typedef __attribute__((ext_vector_type(8))) short short8;
typedef __attribute__((ext_vector_type(4))) float f32x4;

__device__ __forceinline__ float bf2f(unsigned short u) {
    union { unsigned int i; float f; } v; v.i = ((unsigned int)u) << 16; return v.f;
}
__device__ __forceinline__ unsigned short f2bf(float f) {
    __hip_bfloat16 h = __float2bfloat16(f);
    return *reinterpret_cast<unsigned short*>(&h);
}

// ---------------- fp32 -> bf16 bulk convert (vectorized) ----------------
__global__ void k_cvt_bf16(const float4* __restrict__ in, ushort4* __restrict__ out, int n4) {
    int i = blockIdx.x * blockDim.x + threadIdx.x;
    if (i >= n4) return;
    float4 v = in[i];
    ushort4 o;
    o.x = f2bf(v.x); o.y = f2bf(v.y); o.z = f2bf(v.z); o.w = f2bf(v.w);
    out[i] = o;
}

// ---------------- degree histogram ----------------
__global__ void k_hist(const int* __restrict__ dst, unsigned* __restrict__ cnt) {
    int e = blockIdx.x * blockDim.x + threadIdx.x;
    if (e < N_EDGES) atomicAdd(&cnt[dst[e]], 1u);
}

// ---------------- hierarchical exclusive scan ----------------
__global__ __launch_bounds__(SCAN_BLK) void k_scan_local(
        const unsigned* __restrict__ cnt, int* __restrict__ rowptr,
        unsigned* __restrict__ bsum) {
    __shared__ unsigned lds[SCAN_BLK];
    int t = threadIdx.x;
    int gid = blockIdx.x * SCAN_BLK + t;
    unsigned v = (gid < N_NODES) ? cnt[gid] : 0u;
    lds[t] = v;
    __syncthreads();
    for (int d = 1; d < SCAN_BLK; d <<= 1) {
        unsigned add = (t >= d) ? lds[t - d] : 0u;
        __syncthreads();
        lds[t] += add;
        __syncthreads();
    }
    if (gid < N_NODES) rowptr[gid] = (int)(lds[t] - v);   // exclusive within block
    if (t == SCAN_BLK - 1) bsum[blockIdx.x] = lds[t];
}

__global__ void k_scan_bsum(const unsigned* __restrict__ bsum, unsigned* __restrict__ boff) {
    __shared__ unsigned lds[128];
    int t = threadIdx.x;
    unsigned v = (t < SCAN_NB) ? bsum[t] : 0u;
    lds[t] = v;
    __syncthreads();
    for (int d = 1; d < 128; d <<= 1) {
        unsigned add = (t >= d) ? lds[t - d] : 0u;
        __syncthreads();
        lds[t] += add;
        __syncthreads();
    }
    if (t < SCAN_NB) boff[t] = lds[t] - v;
}

__global__ __launch_bounds__(SCAN_BLK) void k_scan_add(
        int* __restrict__ rowptr, const unsigned* __restrict__ boff) {
    int gid = blockIdx.x * SCAN_BLK + threadIdx.x;
    if (gid < N_NODES) rowptr[gid] += (int)boff[blockIdx.x];
    if (gid == 0) rowptr[N_NODES] = N_EDGES;
}

// ---------------- XCD-partitioned scatter ----------------
// region r = blockIdx&7 -> XCD r (round-robin heuristic). All writes to esrc
// slots of region r's nodes come from one XCD -> lines stay in that L2,
// fill densely, write back once. Each chunk of edges is re-read by all 8
// region handlers (dst/src arrays are L3-resident after first sweep).
__global__ __launch_bounds__(256) void k_scatter_xcd(
        const int* __restrict__ src, const int* __restrict__ dst,
        const int* __restrict__ rowptr, unsigned* __restrict__ cur,
        int* __restrict__ esrc) {
    int r = blockIdx.x & (NREG - 1);
    int chunk = blockIdx.x >> 3;
    int base = chunk * CHUNK_SZ;
    int end = base + CHUNK_SZ;
    int rlo = r * REG_SZ;
    int rhi = rlo + REG_SZ;
    for (int e = base + threadIdx.x; e < end; e += 256) {
        int d = dst[e];
        if (d >= rlo && d < rhi) {
            int slot = rowptr[d] + (int)atomicAdd(&cur[d], 1u);
            esrc[slot] = src[e];
        }
    }
}

// ---------------- mean aggregation ----------------
// one wave per node; 16 lanes x short8 (16B) cover a 256B feature row;
// 4 edges in flight per wave-iteration; cross-group reduce via shfl_xor.
__global__ void k_aggregate(const unsigned short* __restrict__ feat,
                            const int* __restrict__ esrc,
                            const int* __restrict__ rowptr,
                            unsigned short* __restrict__ out) {
    int node = blockIdx.x * 4 + (threadIdx.x >> 6);
    if (node >= N_NODES) return;
    int lane = threadIdx.x & 63;
    int sub = lane >> 4;          // which of 4 concurrent edges
    int fl = lane & 15;           // feature lane: feats [fl*8, fl*8+8)
    int s = rowptr[node], e = rowptr[node + 1];
    float acc[8];
#pragma unroll
    for (int q = 0; q < 8; ++q) acc[q] = 0.f;

    for (int j = s + sub; j < e; j += 4) {
        int sv = esrc[j];
        short8 v = *(const short8*)(feat + (size_t)sv * FDIM + fl * 8);
#pragma unroll
        for (int q = 0; q < 8; ++q) acc[q] += bf2f((unsigned short)v[q]);
    }
#pragma unroll
    for (int q = 0; q < 8; ++q) {
        acc[q] += __shfl_xor(acc[q], 16, 64);
        acc[q] += __shfl_xor(acc[q], 32, 64);
    }
    int deg = e - s;
    float inv = 1.0f / (float)(deg > 1 ? deg : 1);
    if (sub == 0) {
        short8 o;
#pragma unroll
        for (int q = 0; q < 8; ++q) o[q] = (short)f2bf(acc[q] * inv);
        *(short8*)(out + (size_t)node * FDIM + fl * 8) = o;
    }
}

// ---------------- pack weights: Bp[col][k] = W[k][col], bf16; pad cols with 0 ----------------
__global__ void k_pack(const float* __restrict__ Wl, const float* __restrict__ Wr,
                       const float* __restrict__ bin, unsigned short* __restrict__ Bp,
                       float* __restrict__ bout, int ncols_out, int ncols_src, int Keach) {
    int K = (Wr != nullptr) ? 2 * Keach : Keach;
    int idx = blockIdx.x * blockDim.x + threadIdx.x;
    if (idx >= ncols_out * K) return;
    int col = idx / K, k = idx % K;
    float v = 0.f;
    if (col < ncols_src)
        v = (k < Keach) ? Wl[(size_t)k * ncols_src + col]
                        : Wr[(size_t)(k - Keach) * ncols_src + col];
    Bp[(size_t)col * K + k] = f2bf(v);
    if (k == 0) bout[col] = (col < ncols_src) ? bin[col] : 0.f;
}

// ---------------- fused layer GEMM: out = relu([A0 | A1] @ Bp^T + bias), bf16 out ----------------
__global__ __launch_bounds__(256) void k_gemm_layer(
        const unsigned short* __restrict__ A0, const unsigned short* __restrict__ A1,
        const unsigned short* __restrict__ Bp, const float* __restrict__ bias,
        unsigned short* __restrict__ out) {
    int wave = threadIdx.x >> 6;
    int lane = threadIdx.x & 63;
    int rowblk = blockIdx.x * 64 + wave * 16;
    int lrow = lane & 15;
    int kgrp = lane >> 4;
    int arow = rowblk + lrow; if (arow > N_NODES - 1) arow = N_NODES - 1;

    f32x4 acc[8];
#pragma unroll
    for (int c = 0; c < 8; ++c) acc[c] = (f32x4){0.f, 0.f, 0.f, 0.f};

#pragma unroll
    for (int kb = 0; kb < 8; ++kb) {
        const unsigned short* Asrc = (kb < 4) ? A0 : A1;
        int kk = (kb & 3) * 32 + kgrp * 8;
        short8 a = *(const short8*)(Asrc + (size_t)arow * FDIM + kk);
        int kB = kb * 32 + kgrp * 8;
#pragma unroll
        for (int c = 0; c < 8; ++c) {
            short8 b = *(const short8*)(Bp + (size_t)(c * 16 + lrow) * 256 + kB);
            acc[c] = __builtin_amdgcn_mfma_f32_16x16x32_bf16(a, b, acc[c], 0, 0, 0);
        }
    }

    int orowbase = rowblk + kgrp * 4;
#pragma unroll
    for (int c = 0; c < 8; ++c) {
        int col = c * 16 + lrow;
        float bv = bias[col];
#pragma unroll
        for (int i = 0; i < 4; ++i) {
            int r = orowbase + i;
            if (r < N_NODES) {
                float v = acc[c][i] + bv;
                v = fmaxf(v, 0.f);
                out[(size_t)r * FDIM + col] = f2bf(v);
            }
        }
    }
}

// ---------------- output GEMM: out = A0 @ Bp^T + bias, fp32 out [N][40], K = 128 ----------------
__global__ __launch_bounds__(256) void k_gemm_out(
        const unsigned short* __restrict__ A0, const unsigned short* __restrict__ Bp,
        const float* __restrict__ bias, float* __restrict__ out) {
    int wave = threadIdx.x >> 6;
    int lane = threadIdx.x & 63;
    int rowblk = blockIdx.x * 64 + wave * 16;
    int lrow = lane & 15;
    int kgrp = lane >> 4;
    int arow = rowblk + lrow; if (arow > N_NODES - 1) arow = N_NODES - 1;

    f32x4 acc[3];
#pragma unroll
    for (int c = 0; c < 3; ++c) acc[c] = (f32x4){0.f, 0.f, 0.f, 0.f};

#pragma unroll
    for (int kb = 0; kb < 4; ++kb) {
        int kk = kb * 32 + kgrp * 8;
        short8 a = *(const short8*)(A0 + (size_t)arow * FDIM + kk);
#pragma unroll
        for (int c = 0; c < 3; ++c) {
            short8 b = *(const short8*)(Bp + (size_t)(c * 16 + lrow) * FDIM + kk);
            acc[c] = __builtin_amdgcn_mfma_f32_16x16x32_bf16(a, b, acc[c], 0, 0, 0);
        }
    }

    int orowbase = rowblk + kgrp * 4;
#pragma unroll
    for (int c = 0; c < 3; ++c) {
        int col = c * 16 + lrow;
        if (col < NCLS) {
            float bv = bias[col];
#pragma unroll
            for (int i = 0; i < 4; ++i) {
                int r = orowbase + i;
                if (r < N_NODES)
                    out[(size_t)r * NCLS + col] = acc[c][i] + bv;
            }
        }
    }
}

extern "C" void kernel_launch(void* const* d_in, const int* in_sizes, int n_in,
                              void* d_out, int out_size, void* d_ws, size_t ws_size,
                              hipStream_t stream) {
    const float* x    = (const float*)d_in[0];
    const int*   ei   = (const int*)d_in[1];
    const float* W1l  = (const float*)d_in[2];
    const float* W1r  = (const float*)d_in[3];
    const float* b1   = (const float*)d_in[4];
    const float* W2l  = (const float*)d_in[5];
    const float* W2r  = (const float*)d_in[6];
    const float* b2   = (const float*)d_in[7];
    const float* Wout = (const float*)d_in[8];
    const float* bout = (const float*)d_in[9];
    const int* src = ei;
    const int* dst = ei + N_EDGES;

    char* ws = (char*)d_ws;
    size_t off = 0;
    auto alloc = [&](size_t bytes) -> void* {
        void* p = ws + off;
        off += (bytes + 255) & ~(size_t)255;
        return p;
    };
    unsigned short* xb   = (unsigned short*)alloc((size_t)N_NODES * FDIM * 2);
    unsigned short* aggn = (unsigned short*)alloc((size_t)N_NODES * FDIM * 2);
    unsigned short* h1   = (unsigned short*)alloc((size_t)N_NODES * FDIM * 2);
    unsigned short* h2   = (unsigned short*)alloc((size_t)N_NODES * FDIM * 2);
    unsigned short* Bp1  = (unsigned short*)alloc((size_t)FDIM * 256 * 2);
    unsigned short* Bp2  = (unsigned short*)alloc((size_t)FDIM * 256 * 2);
    unsigned short* Bp3  = (unsigned short*)alloc((size_t)NCLS_PAD * FDIM * 2);
    float* b1p = (float*)alloc(FDIM * 4);
    float* b2p = (float*)alloc(FDIM * 4);
    float* b3p = (float*)alloc(NCLS_PAD * 4);
    unsigned* cnt  = (unsigned*)alloc((size_t)N_NODES * 4);
    unsigned* cur  = (unsigned*)alloc((size_t)N_NODES * 4);
    int* rowptr    = (int*)alloc((size_t)(N_NODES + 1) * 4);
    int* esrc      = (int*)alloc((size_t)N_EDGES * 4);
    unsigned* bsum = (unsigned*)alloc((size_t)SCAN_NB * 4);
    unsigned* boff = (unsigned*)alloc((size_t)SCAN_NB * 4);

    hipMemsetAsync(cnt, 0, (size_t)N_NODES * 4, stream);
    hipMemsetAsync(cur, 0, (size_t)N_NODES * 4, stream);

    // bf16 copy of x
    int n4 = N_NODES * FDIM / 4;
    k_cvt_bf16<<<(n4 + 255) / 256, 256, 0, stream>>>((const float4*)x, (ushort4*)xb, n4);

    // weight packs
    k_pack<<<(FDIM * 256 + 255) / 256, 256, 0, stream>>>(W1l, W1r, b1, Bp1, b1p, FDIM, FDIM, FDIM);
    k_pack<<<(FDIM * 256 + 255) / 256, 256, 0, stream>>>(W2l, W2r, b2, Bp2, b2p, FDIM, FDIM, FDIM);
    k_pack<<<(NCLS_PAD * FDIM + 255) / 256, 256, 0, stream>>>(Wout, nullptr, bout, Bp3, b3p, NCLS_PAD, NCLS, FDIM);

    // CSR build
    k_hist<<<(N_EDGES + 255) / 256, 256, 0, stream>>>(dst, cnt);
    k_scan_local<<<SCAN_NB, SCAN_BLK, 0, stream>>>(cnt, rowptr, bsum);
    k_scan_bsum<<<1, 128, 0, stream>>>(bsum, boff);
    k_scan_add<<<SCAN_NB, SCAN_BLK, 0, stream>>>(rowptr, boff);
    k_scatter_xcd<<<NREG * NCHUNK, 256, 0, stream>>>(src, dst, rowptr, cur, esrc);

    int aggGrid = (N_NODES + 3) / 4;
    int gemmGrid = (N_NODES + 63) / 64;

    // layer 1
    k_aggregate<<<aggGrid, 256, 0, stream>>>(xb, esrc, rowptr, aggn);
    k_gemm_layer<<<gemmGrid, 256, 0, stream>>>(aggn, xb, Bp1, b1p, h1);
    // layer 2
    k_aggregate<<<aggGrid, 256, 0, stream>>>(h1, esrc, rowptr, aggn);
    k_gemm_layer<<<gemmGrid, 256, 0, stream>>>(aggn, h1, Bp2, b2p, h2);
    // head
    k_gemm_out<<<gemmGrid, 256, 0, stream>>>(h2, Bp3, b3p, (float*)d_out);
}